// Round 7
// baseline (268.141 us; speedup 1.0000x reference)
//
#include <hip/hip_runtime.h>
#include <hip/hip_bf16.h>

// SwitchLinear: B=4,S=2048,D_IN=1024,D_OUT=1024,E=8
// Established contract: ALL inputs fp32, OUTPUT fp32 (out_size=8388609 floats:
// 8192x1024 dense out + aux scalar). ws >= 262400 B. Routing = argmax of fp32
// gate logits; out[t,:] = x[t]@We[top1]^T + be[top1]; aux = mean((mean_gate*E)^2).
// Value GEMM: bf16 MFMA (input-rounding error ~1e-3 << 6.4e-2 threshold).

#define NTOK 8192
#define DIN  1024
#define DOUT 1024
#define NE   8

typedef unsigned short u16;
typedef short  bf16x8 __attribute__((ext_vector_type(8)));
typedef float  f32x4  __attribute__((ext_vector_type(4)));

__device__ __forceinline__ u16 f2bf(float f) {
    __hip_bfloat16 h = __float2bfloat16(f);   // RNE
    return *(u16*)&h;
}

// ws: [0,32) counts | [32,64) mean-gate sums | [256, 262400) per-expert token lists

__global__ __launch_bounds__(256) void gate_kernel(
    const float* __restrict__ x, const float* __restrict__ Wg,
    const float* __restrict__ bg, int* __restrict__ counts,
    float* __restrict__ mg_sum, int* __restrict__ tok_list)
{
    __shared__ float wg_s[NE * DIN];
    __shared__ float mg_s[NE];
    const int tid = threadIdx.x;

    #pragma unroll
    for (int i = 0; i < 4; ++i) {
        int base = tid * 32 + i * 8;
        *(f32x4*)&wg_s[base]     = *(const f32x4*)(Wg + base);
        *(f32x4*)&wg_s[base + 4] = *(const f32x4*)(Wg + base + 4);
    }
    if (tid < NE) mg_s[tid] = 0.f;
    __syncthreads();

    const int wave = tid >> 6;
    const int lane = tid & 63;

    float bgv[NE];
    #pragma unroll
    for (int e = 0; e < NE; ++e) bgv[e] = bg[e];

    #pragma unroll 1
    for (int it = 0; it < 8; ++it) {
        const int t = blockIdx.x * 32 + wave * 8 + it;
        float xv[16];
        const float* xf = x + (size_t)t * DIN;
        #pragma unroll
        for (int c = 0; c < 4; ++c) {
            f32x4 u = *(const f32x4*)(xf + 4 * lane + 256 * c);
            #pragma unroll
            for (int q = 0; q < 4; ++q) xv[c * 4 + q] = u[q];
        }
        float acc[NE];
        #pragma unroll
        for (int e = 0; e < NE; ++e) acc[e] = 0.f;
        #pragma unroll
        for (int e = 0; e < NE; ++e)
            #pragma unroll
            for (int c = 0; c < 4; ++c) {
                f32x4 w = *(const f32x4*)&wg_s[e * DIN + 4 * lane + 256 * c];
                acc[e] = fmaf(w[0], xv[c*4+0], fmaf(w[1], xv[c*4+1],
                         fmaf(w[2], xv[c*4+2], fmaf(w[3], xv[c*4+3], acc[e]))));
            }
        #pragma unroll
        for (int off = 32; off > 0; off >>= 1)
            #pragma unroll
            for (int e = 0; e < NE; ++e) acc[e] += __shfl_xor(acc[e], off, 64);

        float logit[NE];
        #pragma unroll
        for (int e = 0; e < NE; ++e) logit[e] = acc[e] + bgv[e];

        // argmax, first-max wins (matches np/jnp)
        float m = logit[0]; int am = 0;
        #pragma unroll
        for (int e = 1; e < NE; ++e) if (logit[e] > m) { m = logit[e]; am = e; }

        float p[NE], s = 0.f;
        #pragma unroll
        for (int e = 0; e < NE; ++e) { p[e] = __expf(logit[e] - m); s += p[e]; }
        const float inv = 1.f / s;
        if (lane < NE) atomicAdd(&mg_s[lane], p[lane] * inv);
        if (lane == 0) {
            int pos = atomicAdd(&counts[am], 1);
            tok_list[am * NTOK + pos] = t;
        }
    }
    __syncthreads();
    if (tid < NE) atomicAdd(&mg_sum[tid], mg_s[tid]);
}

// ---------------------------------------------------------------------------
// grouped GEMM: per expert e, C[rows(e), 1024] = X[rows(e), :] @ We[e]^T + be[e]
// 128x128 tile, BK=32, 4 waves each 64x64 (4x4 of mfma 16x16x32 bf16).
// fp32 global -> cvt bf16 -> LDS staging; fp32 epilogue writes.
// ---------------------------------------------------------------------------
__global__ __launch_bounds__(256) void moe_gemm(
    const float* __restrict__ x, const float* __restrict__ We,
    const float* __restrict__ be, const int* __restrict__ counts,
    const int* __restrict__ tok_list, float* __restrict__ out)
{
    const int e   = blockIdx.z;
    const int cnt = counts[e];
    const int m0  = blockIdx.y * 128;
    if (m0 >= cnt) return;
    const int n0  = blockIdx.x * 128;

    __shared__ u16 sA[128 * 32];
    __shared__ u16 sB[128 * 32];
    __shared__ int toks[128];

    const int tid = threadIdx.x;
    if (tid < 128) {
        int gr = m0 + tid;
        toks[tid] = (gr < cnt) ? tok_list[e * NTOK + gr] : tok_list[e * NTOK];
    }
    __syncthreads();

    const int lane = tid & 63;
    const int wave = tid >> 6;
    const int wm   = (wave & 1) * 64;
    const int wn   = (wave >> 1) * 64;
    const int lrow = lane & 15;
    const int quad = lane >> 4;

    f32x4 acc[4][4];
    #pragma unroll
    for (int i = 0; i < 4; ++i)
        #pragma unroll
        for (int j = 0; j < 4; ++j) acc[i][j] = (f32x4){0.f, 0.f, 0.f, 0.f};

    const int srow  = tid >> 1;        // 0..127
    const int shalf = (tid & 1) * 16;  // 0 / 16 elems

    const float* xrow = x  + (size_t)toks[srow] * DIN + shalf;
    const float* brow = We + ((size_t)e << 20) + ((size_t)(n0 + srow) << 10) + shalf;

    #pragma unroll 1
    for (int k0 = 0; k0 < DIN; k0 += 32) {
        f32x4 a[4], b[4];
        #pragma unroll
        for (int q = 0; q < 4; ++q) {
            a[q] = *(const f32x4*)(xrow + k0 + 4 * q);
            b[q] = *(const f32x4*)(brow + k0 + 4 * q);
        }
        union { u16 h[16]; uint4 u[2]; } pa, pb;
        #pragma unroll
        for (int q = 0; q < 4; ++q)
            #pragma unroll
            for (int j = 0; j < 4; ++j) {
                pa.h[q * 4 + j] = f2bf(a[q][j]);
                pb.h[q * 4 + j] = f2bf(b[q][j]);
            }
        *(uint4*)&sA[srow * 32 + shalf]     = pa.u[0];
        *(uint4*)&sA[srow * 32 + shalf + 8] = pa.u[1];
        *(uint4*)&sB[srow * 32 + shalf]     = pb.u[0];
        *(uint4*)&sB[srow * 32 + shalf + 8] = pb.u[1];
        __syncthreads();

        bf16x8 af[4], bfr[4];
        #pragma unroll
        for (int i = 0; i < 4; ++i)
            af[i] = *(const bf16x8*)&sA[(wm + i * 16 + lrow) * 32 + quad * 8];
        #pragma unroll
        for (int j = 0; j < 4; ++j)
            bfr[j] = *(const bf16x8*)&sB[(wn + j * 16 + lrow) * 32 + quad * 8];
        #pragma unroll
        for (int i = 0; i < 4; ++i)
            #pragma unroll
            for (int j = 0; j < 4; ++j)
                acc[i][j] = __builtin_amdgcn_mfma_f32_16x16x32_bf16(
                    af[i], bfr[j], acc[i][j], 0, 0, 0);
        __syncthreads();
    }

    // epilogue: D lane map col=lane&15 (N), row=quad*4+r (M); fp32 stores
    #pragma unroll
    for (int j = 0; j < 4; ++j) {
        const int col = n0 + wn + j * 16 + lrow;
        const float bev = be[e * DOUT + col];
        #pragma unroll
        for (int i = 0; i < 4; ++i) {
            #pragma unroll
            for (int r = 0; r < 4; ++r) {
                const int rl = wm + i * 16 + quad * 4 + r;
                if (m0 + rl < cnt) {
                    const int tok = toks[rl];
                    out[((size_t)tok << 10) + col] = acc[i][j][r] + bev;
                }
            }
        }
    }
}

__global__ void aux_kernel(const float* __restrict__ mg, float* __restrict__ out)
{
    if (threadIdx.x == 0) {
        float s = 0.f;
        #pragma unroll
        for (int e = 0; e < NE; ++e) {
            float m = mg[e] * (8.0f / 8192.0f);  // mean_gate * E
            s += m * m;
        }
        out[(size_t)NTOK * DOUT] = s * 0.125f;
    }
}

extern "C" void kernel_launch(void* const* d_in, const int* in_sizes, int n_in,
                              void* d_out, int out_size, void* d_ws, size_t ws_size,
                              hipStream_t stream) {
    const float* x  = (const float*)d_in[0];
    const float* We = (const float*)d_in[1];
    const float* be = (const float*)d_in[2];
    const float* Wg = (const float*)d_in[3];
    const float* bg = (const float*)d_in[4];
    float* out = (float*)d_out;

    int*   counts   = (int*)d_ws;
    float* mg       = (float*)((char*)d_ws + 32);
    int*   tok_list = (int*)((char*)d_ws + 256);

    hipMemsetAsync(d_ws, 0, 256, stream);
    gate_kernel<<<256, 256, 0, stream>>>(x, Wg, bg, counts, mg, tok_list);
    moe_gemm<<<dim3(8, 64, 8), 256, 0, stream>>>(x, We, be, counts, tok_list, out);
    aux_kernel<<<1, 64, 0, stream>>>(mg, out);
}